// Round 14
// baseline (9716.091 us; speedup 1.0000x reference)
//
#include <hip/hip_runtime.h>

typedef _Float16 half8 __attribute__((ext_vector_type(8)));
typedef _Float16 half4v __attribute__((ext_vector_type(4)));
typedef float float4v __attribute__((ext_vector_type(4)));

#define HID 2048
#define EMBD 2048
#define BATCH 128
#define TSTEPS 256
#define STEP ((size_t)BATCH * HID)
#define LOOK 4

// ---------------- small prep kernels ----------------
__global__ __launch_bounds__(256) void cast_f16_kernel(const float* __restrict__ src,
                                                       _Float16* __restrict__ dst, int n) {
    int i = (blockIdx.x * 256 + threadIdx.x) * 4;
    int stride = gridDim.x * 256 * 4;
    for (; i < n; i += stride) {
        float4v v = *(const float4v*)(src + i);
        half4v h;
        h[0] = (_Float16)v[0]; h[1] = (_Float16)v[1];
        h[2] = (_Float16)v[2]; h[3] = (_Float16)v[3];
        *(half4v*)(dst + i) = h;
    }
}

// ---------------- Phase B: persistent scan with FUSED phaseA tiles ----------------
// R9 protocol EXACTLY (proven 1950us): 256 blocks x 256 thr; gid=bx&3 rows
// [32g,+32); sub=bx>>2 cols [32c,+32); wave (pr=w>>1, kh=w&1) = 16 rows x 32 cols x
// k-half; LDS part-reduce (stride 33); slot-chain xb (257 slots): bias[s] in slot
// s+1 (sc1 reads), h_{s+1} -> slot s (sc1 stores); gate = 64 u32 flags/group,
// all-wave unpaced poll; post-gate h reads plain cacheable (L2-shared per XCD).
// NEW: at end of step s each block computes ITS OWN bias tile for timestep t=s+LOOK
// (32x32 out x K=2048; emb fp32->f16 cvt + W_ih fp16, swapped-operand MFMA, no LDS)
// and sc1-stores it into slot t+1. Only this block ever reads that tile => zero new
// synchronization (program order + existing per-step vmcnt drains). Work sits in
// the gate wait-window => period ~unchanged; phaseA's ~430us serial phase deleted.
__global__ __launch_bounds__(256, 1) void scan_kernel(_Float16* __restrict__ xb,
                                                      const _Float16* __restrict__ whh,
                                                      const _Float16* __restrict__ wih,
                                                      const float* __restrict__ emb,
                                                      const int* __restrict__ xtok,
                                                      const float* __restrict__ bih,
                                                      const float* __restrict__ bhh,
                                                      float* __restrict__ hlast,
                                                      unsigned* __restrict__ flags) {
    __shared__ __align__(16) _Float16 Wl[32 * 2048];  // 128 KB
    __shared__ float part[4][16 * 33];

    const int tid = threadIdx.x;
    const int bx = blockIdx.x;
    const int gid = bx & 3, sub = bx >> 2;
    const int m0 = gid * 32, n0 = sub * 32;
    const int lane = tid & 63, w = tid >> 6;
    const int ln15 = lane & 15, kg = lane >> 4;
    const int pr = w >> 1, kh = w & 1;

    // stage W_hh[n0..n0+32) x [0..2048): byte = col*4096 + ((k*2) ^ ((col&7)<<4))
    for (int it = 0; it < 32; ++it) {
        int c = it * 256 + tid;
        int col = c >> 8, ch = c & 255;
        half8 v = *(const half8*)(whh + (long)(n0 + col) * HID + ch * 8);
        *(half8*)((char*)Wl + col * 4096 + ((ch * 16) ^ ((col & 7) << 4))) = v;
    }
    __syncthreads();

    unsigned* gfl = flags + gid * 64;                       // 64 flags per group
    const unsigned long long* gfl64 = (const unsigned long long*)gfl;
    const size_t arow = (size_t)(m0 + pr * 16 + ln15);      // h row this lane loads
    const int wb0 = ln15 * 4096, wb1 = (16 + ln15) * 4096;  // W_hh LDS row bases
    const int swz = (ln15 & 7) << 4;
    const int kb = kh * 2048;                               // k-half byte offset
    const int rp = tid >> 7, ridx = tid & 127;              // reduce/output mapping
    const int rrow = ridx >> 3, rc4 = (ridx & 7) * 4;
    const size_t oidx = (size_t)(m0 + rp * 16 + rrow) * HID + n0 + rc4;

    // ---- fused-phaseA per-thread constants (proven phaseA fragment mapping) ----
    const int trowg = m0 + pr * 16 + ln15;                  // tile row (batch row)
    const int tcol = n0 + kh * 16 + kg * 4;                 // tile col base (4 wide)
    const _Float16* bwrow = wih + (size_t)(n0 + kh * 16 + ln15) * EMBD;
    float4v breg = *(const float4v*)(bih + tcol);
    { float4v b2 = *(const float4v*)(bhh + tcol); breg = breg + b2; }

    auto tileA = [&](int t) {
        int tok = xtok[t * BATCH + trowg];
        const float* ae = emb + (size_t)tok * EMBD;
        float4v ta0 = (float4v){0.f, 0.f, 0.f, 0.f};
        float4v ta1 = (float4v){0.f, 0.f, 0.f, 0.f};
#pragma unroll 16
        for (int j = 0; j < 64; ++j) {
            int k = j * 32 + kg * 8;
            float4v e0 = *(const float4v*)(ae + k);
            float4v e1 = *(const float4v*)(ae + k + 4);
            half8 a;
#pragma unroll
            for (int q = 0; q < 4; ++q) { a[q] = (_Float16)e0[q]; a[4 + q] = (_Float16)e1[q]; }
            half8 bw = *(const half8*)(bwrow + k);
            if (j & 1) ta1 = __builtin_amdgcn_mfma_f32_16x16x32_f16(bw, a, ta1, 0, 0, 0);
            else       ta0 = __builtin_amdgcn_mfma_f32_16x16x32_f16(bw, a, ta0, 0, 0, 0);
        }
        union { half4v h; unsigned long long u; } pk;
#pragma unroll
        for (int r = 0; r < 4; ++r) pk.h[r] = (_Float16)(ta0[r] + ta1[r] + breg[r]);
        __hip_atomic_store((unsigned long long*)(xb + (size_t)(t + 1) * STEP +
                                                 (size_t)trowg * HID + tcol),
                           pk.u, __ATOMIC_RELAXED, __HIP_MEMORY_SCOPE_AGENT);
    };

    // prologue: bias tiles for timesteps 0..LOOK-1, drained before first bias read
    for (int t = 0; t < LOOK; ++t) tileA(t);
    asm volatile("s_waitcnt vmcnt(0)" ::: "memory");

    for (int s = 0; s < TSTEPS; ++s) {
        // bias[s] from slot s+1 — sc1 bypass (written by own tileA(s) earlier)
        unsigned long long xbits = __hip_atomic_load(
            (const unsigned long long*)(xb + (size_t)(s + 1) * STEP + oidx),
            __ATOMIC_RELAXED, __HIP_MEMORY_SCOPE_AGENT);

        float4v acc0 = (float4v){0.f, 0.f, 0.f, 0.f};
        float4v acc1 = (float4v){0.f, 0.f, 0.f, 0.f};
        if (s > 0) {
            // ---- gate: all 64 producer flags of this group >= s (all-wave poll)
            for (;;) {
                bool ok = true;
                if (lane < 32) {
                    unsigned long long v = __hip_atomic_load(gfl64 + lane,
                                            __ATOMIC_RELAXED, __HIP_MEMORY_SCOPE_AGENT);
                    ok = ((unsigned)v >= (unsigned)s) && ((unsigned)(v >> 32) >= (unsigned)s);
                }
                if (__all(ok)) break;
                __builtin_amdgcn_s_sleep(2);
            }
            asm volatile("" ::: "memory");        // no hoisting h loads above gate
            __builtin_amdgcn_sched_barrier(0);

            // ---- h_s from slot s-1: plain cacheable loads (L2-shared per XCD)
            const _Float16* hrow = xb + (size_t)(s - 1) * STEP + arow * HID + kh * 1024;
#pragma unroll
            for (int j = 0; j < 32; ++j) {
                half8 a = *(const half8*)(hrow + j * 32 + kg * 8);
                int k2 = kb + j * 64 + kg * 16;
                half8 b0 = *(half8*)((char*)Wl + wb0 + (k2 ^ swz));
                half8 b1 = *(half8*)((char*)Wl + wb1 + (k2 ^ swz));
                acc0 = __builtin_amdgcn_mfma_f32_16x16x32_f16(a, b0, acc0, 0, 0, 0);
                acc1 = __builtin_amdgcn_mfma_f32_16x16x32_f16(a, b1, acc1, 0, 0, 0);
            }
            // partials to LDS (stride 33)
#pragma unroll
            for (int r = 0; r < 4; ++r) {
                part[w][(kg * 4 + r) * 33 + ln15] = acc0[r];
                part[w][(kg * 4 + r) * 33 + 16 + ln15] = acc1[r];
            }
        }

        float s0 = 0.f, s1 = 0.f, s2 = 0.f, s3 = 0.f;
        if (s > 0) {
            __syncthreads();
            const float* p0 = &part[2 * rp][rrow * 33 + rc4];
            const float* p1 = &part[2 * rp + 1][rrow * 33 + rc4];
            s0 = p0[0] + p1[0]; s1 = p0[1] + p1[1];
            s2 = p0[2] + p1[2]; s3 = p0[3] + p1[3];
        }
        union { unsigned long long u; half4v h; } xbv; xbv.u = xbits;
        float o0 = tanhf(s0 + (float)xbv.h[0]);
        float o1 = tanhf(s1 + (float)xbv.h[1]);
        float o2 = tanhf(s2 + (float)xbv.h[2]);
        float o3 = tanhf(s3 + (float)xbv.h[3]);

        if (s < TSTEPS - 1) {
            // h_{s+1} -> slot s (sc1 fire-and-forget)
            union { half4v h; unsigned long long u; } pk;
            pk.h[0] = (_Float16)o0; pk.h[1] = (_Float16)o1;
            pk.h[2] = (_Float16)o2; pk.h[3] = (_Float16)o3;
            __hip_atomic_store((unsigned long long*)(xb + (size_t)s * STEP + oidx),
                               pk.u, __ATOMIC_RELAXED, __HIP_MEMORY_SCOPE_AGENT);
            // syncthreads drains vmcnt: all h stores acked before the flag; also
            // the WAR guard for part[].
            __syncthreads();
            if (tid == 0)
                __hip_atomic_store(&gfl[sub], (unsigned)(s + 1),
                                   __ATOMIC_RELAXED, __HIP_MEMORY_SCOPE_AGENT);
        } else {
            float4v f = {o0, o1, o2, o3};
            *(float4v*)(hlast + oidx) = f;
        }

        // ---- fused phaseA tile for timestep s+LOOK, in the gate wait-window ----
        if (s + LOOK < TSTEPS) tileA(s + LOOK);
    }
}

// ---------------- head ----------------
// fc1 tiled: 16 blocks x 8 batch rows; fc1w read ONCE per block (32MB total)
__global__ __launch_bounds__(256) void fc1_kernel(const float* __restrict__ hlast,
                                                  const float* __restrict__ w,
                                                  const float* __restrict__ b,
                                                  float* __restrict__ z) {
    __shared__ float hs[8][256];
    const int blk = blockIdx.x;
    const int j = threadIdx.x;
    const int bb0 = blk * 8;
    float acc[8];
#pragma unroll
    for (int r = 0; r < 8; ++r) acc[r] = 0.f;
    const float* wr = w + (long)j * HID;
    const int sr = j >> 5, sc = (j & 31) * 8;

    for (int kt = 0; kt < 8; ++kt) {
        __syncthreads();
        float4v h0 = *(const float4v*)(hlast + (long)(bb0 + sr) * HID + kt * 256 + sc);
        float4v h1 = *(const float4v*)(hlast + (long)(bb0 + sr) * HID + kt * 256 + sc + 4);
        *(float4v*)&hs[sr][sc] = h0;
        *(float4v*)&hs[sr][sc + 4] = h1;
        __syncthreads();
        for (int k = 0; k < 256; k += 4) {
            float4v wv = *(const float4v*)(wr + kt * 256 + k);
#pragma unroll
            for (int r = 0; r < 8; ++r) {
                float4v hv = *(const float4v*)&hs[r][k];
                acc[r] += hv[0] * wv[0] + hv[1] * wv[1] + hv[2] * wv[2] + hv[3] * wv[3];
            }
        }
    }
    float bj = b[j];
#pragma unroll
    for (int r = 0; r < 8; ++r) z[(bb0 + r) * 256 + j] = fmaxf(acc[r] + bj, 0.f);
}

__global__ __launch_bounds__(256) void fc2_kernel(const float* __restrict__ z,
                                                  const float* __restrict__ w,
                                                  const float* __restrict__ b,
                                                  float* __restrict__ out) {
    __shared__ float red[4];
    int bb = blockIdx.x;
    int tid = threadIdx.x;
    float zv = z[bb * 256 + tid];
    for (int c = 0; c < 3; ++c) {
        float s = zv * w[c * 256 + tid];
        for (int off = 32; off > 0; off >>= 1) s += __shfl_down(s, off, 64);
        if ((tid & 63) == 0) red[tid >> 6] = s;
        __syncthreads();
        if (tid == 0) out[bb * 3 + c] = red[0] + red[1] + red[2] + red[3] + b[c];
        __syncthreads();
    }
}

// ---------------- launch ----------------
extern "C" void kernel_launch(void* const* d_in, const int* in_sizes, int n_in,
                              void* d_out, int out_size, void* d_ws, size_t ws_size,
                              hipStream_t stream) {
    const int*   x    = (const int*)d_in[0];
    const float* emb  = (const float*)d_in[1];
    const float* Wih  = (const float*)d_in[2];
    const float* Whh  = (const float*)d_in[3];
    const float* bih  = (const float*)d_in[4];
    const float* bhh  = (const float*)d_in[5];
    const float* fc1w = (const float*)d_in[6];
    const float* fc1b = (const float*)d_in[7];
    const float* fc2w = (const float*)d_in[8];
    const float* fc2b = (const float*)d_in[9];
    float* out = (float*)d_out;

    char* ws = (char*)d_ws;
    size_t off = 0;
    _Float16* xb    = (_Float16*)(ws + off); off += 257 * STEP * 2;         // 134.7 MB
    _Float16* wih16 = (_Float16*)(ws + off); off += (size_t)HID * EMBD * 2; // 8 MB
    _Float16* whh16 = (_Float16*)(ws + off); off += (size_t)HID * HID * 2;  // 8 MB
    float*    hlast = (float*)(ws + off);    off += (size_t)BATCH * HID * 4;
    float*    z     = (float*)(ws + off);    off += (size_t)BATCH * 256 * 4;
    unsigned* flags = (unsigned*)(ws + off); off += 4 * 64 * 4;  // 1 KB

    hipMemsetAsync(flags, 0, 4 * 64 * 4, stream);

    cast_f16_kernel<<<4096, 256, 0, stream>>>(Wih, wih16, HID * EMBD);
    cast_f16_kernel<<<4096, 256, 0, stream>>>(Whh, whh16, HID * HID);

    void* args[] = {(void*)&xb, (void*)&whh16, (void*)&wih16, (void*)&emb,
                    (void*)&x, (void*)&bih, (void*)&bhh, (void*)&hlast, (void*)&flags};
    hipLaunchCooperativeKernel((const void*)scan_kernel, dim3(256), dim3(256), args, 0, stream);

    fc1_kernel<<<16, 256, 0, stream>>>(hlast, fc1w, fc1b, z);
    fc2_kernel<<<BATCH, 256, 0, stream>>>(z, fc2w, fc2b, out);
}

// Round 15
// 4354.753 us; speedup vs baseline: 2.2311x; 2.2311x over previous
//
#include <hip/hip_runtime.h>

typedef _Float16 half8 __attribute__((ext_vector_type(8)));
typedef _Float16 half4v __attribute__((ext_vector_type(4)));
typedef float float4v __attribute__((ext_vector_type(4)));

#define HID 2048
#define EMBD 2048
#define BATCH 128
#define TSTEPS 256
#define STEP ((size_t)BATCH * HID)

// ---------------- small prep kernels ----------------
__global__ __launch_bounds__(256) void cast_f16_kernel(const float* __restrict__ src,
                                                       _Float16* __restrict__ dst, int n) {
    int i = (blockIdx.x * 256 + threadIdx.x) * 4;
    int stride = gridDim.x * 256 * 4;
    for (; i < n; i += stride) {
        float4v v = *(const float4v*)(src + i);
        half4v h;
        h[0] = (_Float16)v[0]; h[1] = (_Float16)v[1];
        h[2] = (_Float16)v[2]; h[3] = (_Float16)v[3];
        *(half4v*)(dst + i) = h;
    }
}

__global__ __launch_bounds__(256) void bias_kernel(const float* __restrict__ a,
                                                   const float* __restrict__ b,
                                                   float* __restrict__ dst) {
    int i = blockIdx.x * 256 + threadIdx.x;
    if (i < HID) dst[i] = a[i] + b[i];
}

// ---------------- Phase A: slots 1..256 of xb = gather(emb,x) @ W_ih^T + bias ----------
__global__ __launch_bounds__(256) void phaseA_kernel(const int* __restrict__ x,
                                                     const float* __restrict__ emb,
                                                     const _Float16* __restrict__ w16,
                                                     const float* __restrict__ bias,
                                                     _Float16* __restrict__ xproj) {
    __shared__ __align__(16) _Float16 As[128 * 64];
    __shared__ __align__(16) _Float16 Bs[128 * 64];

    const int tid = threadIdx.x;
    const int bx  = blockIdx.x;
    const int nt = bx & 15, mt = bx >> 4;
    const long m0 = (long)mt * 128;
    const long n0 = (long)nt * 128;
    const int lane = tid & 63, w = tid >> 6;
    const int ln15 = lane & 15, kg = lane >> 4;
    const int wr = (w >> 1) * 64, wc = (w & 1) * 64;

    int xr[4];
#pragma unroll
    for (int it = 0; it < 4; ++it) xr[it] = x[m0 + ((it * 256 + tid) >> 3)];

    float4v acc[4][4];
#pragma unroll
    for (int m = 0; m < 4; ++m)
#pragma unroll
        for (int n = 0; n < 4; ++n) acc[m][n] = (float4v){0.f, 0.f, 0.f, 0.f};

    for (int kt = 0; kt < 32; ++kt) {
        __syncthreads();
#pragma unroll
        for (int it = 0; it < 4; ++it) {
            int c = it * 256 + tid;
            const float* src = emb + (long)xr[it] * EMBD + kt * 64 + (c & 7) * 8;
            float4v v0 = *(const float4v*)src;
            float4v v1 = *(const float4v*)(src + 4);
            half8 hv;
#pragma unroll
            for (int q = 0; q < 4; ++q) { hv[q] = (_Float16)v0[q]; hv[4 + q] = (_Float16)v1[q]; }
            *(half8*)(&As[c * 8]) = hv;
        }
#pragma unroll
        for (int it = 0; it < 4; ++it) {
            int c = it * 256 + tid;
            const _Float16* src = w16 + (n0 + (c >> 3)) * (long)EMBD + kt * 64 + (c & 7) * 8;
            *(half8*)(&Bs[c * 8]) = *(const half8*)src;
        }
        __syncthreads();
#pragma unroll
        for (int kk = 0; kk < 2; ++kk) {
            half8 a[4], b[4];
#pragma unroll
            for (int m = 0; m < 4; ++m)
                a[m] = *(half8*)(&As[(wr + m * 16 + ln15) * 64 + kk * 32 + kg * 8]);
#pragma unroll
            for (int n = 0; n < 4; ++n)
                b[n] = *(half8*)(&Bs[(wc + n * 16 + ln15) * 64 + kk * 32 + kg * 8]);
            // swapped operands -> transposed fragment: lane holds 4 consecutive cols
#pragma unroll
            for (int m = 0; m < 4; ++m)
#pragma unroll
                for (int n = 0; n < 4; ++n)
                    acc[m][n] = __builtin_amdgcn_mfma_f32_16x16x32_f16(b[n], a[m], acc[m][n], 0, 0, 0);
        }
    }
#pragma unroll
    for (int m = 0; m < 4; ++m) {
        long mg = m0 + wr + m * 16 + ln15;
#pragma unroll
        for (int n = 0; n < 4; ++n) {
            int nb = (int)n0 + wc + n * 16 + kg * 4;
            float4v bv = *(const float4v*)(bias + nb);
            union { half4v h; unsigned long long u; } pk;
#pragma unroll
            for (int r = 0; r < 4; ++r) pk.h[r] = (_Float16)(acc[m][n][r] + bv[r]);
            *(unsigned long long*)(xproj + mg * HID + nb) = pk.u;
        }
    }
}

// ---------------- Phase B: XCD-local persistent scan ----------------
// 256 blocks x 256 thr, 1/CU (128KB LDS forces it). Self-assign via HW_REG_XCC_ID +
// per-XCD claim (R13-proven; pigeonhole => exactly 32 blocks/XCD).
// Group = XCD: owns batch rows [16*xcd,+16). Block c: cols [64c,+64), FULL K=2048.
// W slice 256 KB = 128 KB LDS (K in [0,1024), XOR-swizzled) + 128 KB persistent
// VGPRs (K in [1024,2048): 32 x half8 = 128 VGPR/lane, statically indexed).
// Wave w: 16 rows x 16 cols [64c+16w,+16) x full K, swapped-operand MFMA ->
// lane stores one 8B h-quad. NO __syncthreads in loop, no part-reduce.
// All h exchange is XCD-LOCAL: plain stores -> own L2 (dirty); same-XCD consumers
// plain-load -> L2 hit. L1 staleness impossible: every slot address is cacheably
// read exactly once per block (bias reads are sc1-bypass; stores don't fill L1).
// Flags (proven sc1/LLC): wave drains own vmcnt, posts own flag; gate = 128
// wave-flags of own XCD, one u64 per lane. Slot-chain: bias[s] in slot s+1 (sc1),
// h_{s+1} -> slot s (plain; owner read bias[s-1] there at s-1 => dead, same block).
__global__ __launch_bounds__(256, 1) void scan_kernel(_Float16* __restrict__ xb,
                                                      const _Float16* __restrict__ whh,
                                                      float* __restrict__ hlast,
                                                      unsigned* __restrict__ ctrs,
                                                      unsigned* __restrict__ flags) {
    __shared__ __align__(16) _Float16 Wl[64 * 1024];  // 128 KB (K-low)
    __shared__ int sh_ids[2];

    const int tid = threadIdx.x;
    if (tid == 0) {
        unsigned xcc;
        asm volatile("s_getreg_b32 %0, hwreg(HW_REG_XCC_ID)" : "=s"(xcc));
        sh_ids[0] = (int)xcc;
        sh_ids[1] = (int)atomicAdd(&ctrs[xcc * 32], 1u);
    }
    __syncthreads();
    const int xcd = sh_ids[0], c = sh_ids[1];
    const int m0 = xcd * 16;
    const long n0 = (long)c * 64;

    // stage W K-low for cols [n0,+64): byte = col*2048 + ((k*2) ^ ((col&7)<<4))
    for (int it = 0; it < 32; ++it) {
        int idx = it * 256 + tid;
        int col = idx >> 7, ch = idx & 127;
        half8 v = *(const half8*)(whh + (n0 + col) * (long)HID + ch * 8);
        *(half8*)((char*)Wl + col * 2048 + ((ch * 16) ^ ((col & 7) << 4))) = v;
    }

    const int lane = tid & 63, w = tid >> 6;
    const int ln15 = lane & 15, kg = lane >> 4;
    const int swz = (ln15 & 7) << 4;
    const int wbyte = (16 * w + ln15) * 2048;

    // W K-high persistent registers: 32 x half8 = 128 VGPR
    half8 wreg[32];
    {
        const _Float16* wsrc = whh + (n0 + 16 * w + ln15) * (long)HID + 1024 + kg * 8;
#pragma unroll
        for (int j = 0; j < 32; ++j) wreg[j] = *(const half8*)(wsrc + j * 32);
    }
    __syncthreads();

    unsigned* gfl = flags + xcd * 128;                       // 128 wave flags per XCD
    const unsigned long long* gfl64 = (const unsigned long long*)gfl;
    const size_t hrowoff = (size_t)(m0 + ln15) * HID;        // h row (load & output)
    const int ocol = (int)n0 + 16 * w + kg * 4;              // output col base (4)
    const size_t oidx = hrowoff + ocol;
    const int fidx = c * 4 + w;                              // this wave's flag

    for (int s = 0; s < TSTEPS; ++s) {
        // bias[s] from slot s+1 — sc1 bypass (never enters L1/L2)
        unsigned long long xbits = __hip_atomic_load(
            (const unsigned long long*)(xb + (size_t)(s + 1) * STEP + oidx),
            __ATOMIC_RELAXED, __HIP_MEMORY_SCOPE_AGENT);

        float4v acc0 = (float4v){0.f, 0.f, 0.f, 0.f};
        float4v acc1 = (float4v){0.f, 0.f, 0.f, 0.f};
        if (s > 0) {
            // gate: all 128 wave flags of own XCD >= s (one u64 per lane)
            for (;;) {
                unsigned long long v = __hip_atomic_load(gfl64 + lane,
                                        __ATOMIC_RELAXED, __HIP_MEMORY_SCOPE_AGENT);
                bool ok = ((unsigned)v >= (unsigned)s) && ((unsigned)(v >> 32) >= (unsigned)s);
                if (__all(ok)) break;
                __builtin_amdgcn_s_sleep(2);
            }
            asm volatile("" ::: "memory");        // no hoisting h loads above gate
            __builtin_amdgcn_sched_barrier(0);

            // h_s from slot s-1: PLAIN loads -> own-XCD L2 (L1 shares across 4 waves)
            const _Float16* hrow = xb + (size_t)(s - 1) * STEP + hrowoff + kg * 8;
#pragma unroll
            for (int j = 0; j < 32; ++j) {
                half8 a = *(const half8*)(hrow + j * 32);
                half8 b = *(half8*)((char*)Wl + wbyte + ((j * 64 + kg * 16) ^ swz));
                if (j & 1) acc1 = __builtin_amdgcn_mfma_f32_16x16x32_f16(b, a, acc1, 0, 0, 0);
                else       acc0 = __builtin_amdgcn_mfma_f32_16x16x32_f16(b, a, acc0, 0, 0, 0);
            }
#pragma unroll
            for (int j = 0; j < 32; ++j) {
                half8 a = *(const half8*)(hrow + 1024 + j * 32);
                if (j & 1) acc1 = __builtin_amdgcn_mfma_f32_16x16x32_f16(wreg[j], a, acc1, 0, 0, 0);
                else       acc0 = __builtin_amdgcn_mfma_f32_16x16x32_f16(wreg[j], a, acc0, 0, 0, 0);
            }
        }

        union { unsigned long long u; half4v h; } xbv; xbv.u = xbits;
        float o0 = tanhf(acc0[0] + acc1[0] + (float)xbv.h[0]);
        float o1 = tanhf(acc0[1] + acc1[1] + (float)xbv.h[1]);
        float o2 = tanhf(acc0[2] + acc1[2] + (float)xbv.h[2]);
        float o3 = tanhf(acc0[3] + acc1[3] + (float)xbv.h[3]);

        if (s < TSTEPS - 1) {
            // h_{s+1} -> slot s: PLAIN store (dirty in own L2; consumers same XCD)
            union { half4v h; unsigned long long u; } pk;
            pk.h[0] = (_Float16)o0; pk.h[1] = (_Float16)o1;
            pk.h[2] = (_Float16)o2; pk.h[3] = (_Float16)o3;
            *(unsigned long long*)(xb + (size_t)s * STEP + oidx) = pk.u;
            // own stores acked at L2, then post own wave flag (sc1)
            asm volatile("s_waitcnt vmcnt(0)" ::: "memory");
            if (lane == 0)
                __hip_atomic_store(&gfl[fidx], (unsigned)(s + 1),
                                   __ATOMIC_RELAXED, __HIP_MEMORY_SCOPE_AGENT);
        } else {
            float4v f = {o0, o1, o2, o3};
            *(float4v*)(hlast + oidx) = f;
        }
    }
}

// ---------------- head ----------------
// fc1 tiled: 16 blocks x 8 batch rows; fc1w read ONCE per block (32MB total)
__global__ __launch_bounds__(256) void fc1_kernel(const float* __restrict__ hlast,
                                                  const float* __restrict__ w,
                                                  const float* __restrict__ b,
                                                  float* __restrict__ z) {
    __shared__ float hs[8][256];
    const int blk = blockIdx.x;
    const int j = threadIdx.x;
    const int bb0 = blk * 8;
    float acc[8];
#pragma unroll
    for (int r = 0; r < 8; ++r) acc[r] = 0.f;
    const float* wr = w + (long)j * HID;
    const int sr = j >> 5, sc = (j & 31) * 8;

    for (int kt = 0; kt < 8; ++kt) {
        __syncthreads();
        float4v h0 = *(const float4v*)(hlast + (long)(bb0 + sr) * HID + kt * 256 + sc);
        float4v h1 = *(const float4v*)(hlast + (long)(bb0 + sr) * HID + kt * 256 + sc + 4);
        *(float4v*)&hs[sr][sc] = h0;
        *(float4v*)&hs[sr][sc + 4] = h1;
        __syncthreads();
        for (int k = 0; k < 256; k += 4) {
            float4v wv = *(const float4v*)(wr + kt * 256 + k);
#pragma unroll
            for (int r = 0; r < 8; ++r) {
                float4v hv = *(const float4v*)&hs[r][k];
                acc[r] += hv[0] * wv[0] + hv[1] * wv[1] + hv[2] * wv[2] + hv[3] * wv[3];
            }
        }
    }
    float bj = b[j];
#pragma unroll
    for (int r = 0; r < 8; ++r) z[(bb0 + r) * 256 + j] = fmaxf(acc[r] + bj, 0.f);
}

__global__ __launch_bounds__(256) void fc2_kernel(const float* __restrict__ z,
                                                  const float* __restrict__ w,
                                                  const float* __restrict__ b,
                                                  float* __restrict__ out) {
    __shared__ float red[4];
    int bb = blockIdx.x;
    int tid = threadIdx.x;
    float zv = z[bb * 256 + tid];
    for (int c = 0; c < 3; ++c) {
        float s = zv * w[c * 256 + tid];
        for (int off = 32; off > 0; off >>= 1) s += __shfl_down(s, off, 64);
        if ((tid & 63) == 0) red[tid >> 6] = s;
        __syncthreads();
        if (tid == 0) out[bb * 3 + c] = red[0] + red[1] + red[2] + red[3] + b[c];
        __syncthreads();
    }
}

// ---------------- launch ----------------
extern "C" void kernel_launch(void* const* d_in, const int* in_sizes, int n_in,
                              void* d_out, int out_size, void* d_ws, size_t ws_size,
                              hipStream_t stream) {
    const int*   x    = (const int*)d_in[0];
    const float* emb  = (const float*)d_in[1];
    const float* Wih  = (const float*)d_in[2];
    const float* Whh  = (const float*)d_in[3];
    const float* bih  = (const float*)d_in[4];
    const float* bhh  = (const float*)d_in[5];
    const float* fc1w = (const float*)d_in[6];
    const float* fc1b = (const float*)d_in[7];
    const float* fc2w = (const float*)d_in[8];
    const float* fc2b = (const float*)d_in[9];
    float* out = (float*)d_out;

    char* ws = (char*)d_ws;
    size_t off = 0;
    _Float16* xb    = (_Float16*)(ws + off); off += 257 * STEP * 2;         // 134.7 MB
    _Float16* wih16 = (_Float16*)(ws + off); off += (size_t)HID * EMBD * 2; // 8 MB
    _Float16* whh16 = (_Float16*)(ws + off); off += (size_t)HID * HID * 2;  // 8 MB
    float*    bias  = (float*)(ws + off);    off += (size_t)HID * 4;
    float*    hlast = (float*)(ws + off);    off += (size_t)BATCH * HID * 4;
    float*    z     = (float*)(ws + off);    off += (size_t)BATCH * 256 * 4;
    unsigned* ctrs  = (unsigned*)(ws + off); off += 8 * 32 * 4;   // per-XCD claim
    unsigned* flags = (unsigned*)(ws + off); off += 8 * 128 * 4;  // per-XCD wave flags

    hipMemsetAsync(ctrs, 0, (8 * 32 + 8 * 128) * 4, stream);

    cast_f16_kernel<<<4096, 256, 0, stream>>>(Wih, wih16, HID * EMBD);
    cast_f16_kernel<<<4096, 256, 0, stream>>>(Whh, whh16, HID * HID);
    bias_kernel<<<8, 256, 0, stream>>>(bih, bhh, bias);

    // phaseA writes bias[s] into slot s+1
    phaseA_kernel<<<4096, 256, 0, stream>>>(x, emb, wih16, bias, xb + STEP);

    void* args[] = {(void*)&xb, (void*)&whh16, (void*)&hlast, (void*)&ctrs, (void*)&flags};
    hipLaunchCooperativeKernel((const void*)scan_kernel, dim3(256), dim3(256), args, 0, stream);

    fc1_kernel<<<16, 256, 0, stream>>>(hlast, fc1w, fc1b, z);
    fc2_kernel<<<BATCH, 256, 0, stream>>>(z, fc2w, fc2b, out);
}

// Round 16
// 2671.723 us; speedup vs baseline: 3.6366x; 1.6299x over previous
//
#include <hip/hip_runtime.h>

typedef _Float16 half8 __attribute__((ext_vector_type(8)));
typedef _Float16 half4v __attribute__((ext_vector_type(4)));
typedef float float4v __attribute__((ext_vector_type(4)));

#define HID 2048
#define EMBD 2048
#define BATCH 128
#define TSTEPS 256
#define STEP ((size_t)BATCH * HID)

// ---------------- small prep kernels ----------------
__global__ __launch_bounds__(256) void cast_f16_kernel(const float* __restrict__ src,
                                                       _Float16* __restrict__ dst, int n) {
    int i = (blockIdx.x * 256 + threadIdx.x) * 4;
    int stride = gridDim.x * 256 * 4;
    for (; i < n; i += stride) {
        float4v v = *(const float4v*)(src + i);
        half4v h;
        h[0] = (_Float16)v[0]; h[1] = (_Float16)v[1];
        h[2] = (_Float16)v[2]; h[3] = (_Float16)v[3];
        *(half4v*)(dst + i) = h;
    }
}

__global__ __launch_bounds__(256) void bias_kernel(const float* __restrict__ a,
                                                   const float* __restrict__ b,
                                                   float* __restrict__ dst) {
    int i = blockIdx.x * 256 + threadIdx.x;
    if (i < HID) dst[i] = a[i] + b[i];
}

// ---------------- Phase A: slots 1..256 of xb = gather(emb,x) @ W_ih^T + bias ----------
// (R9-proven manual staging)
__global__ __launch_bounds__(256) void phaseA_kernel(const int* __restrict__ x,
                                                     const float* __restrict__ emb,
                                                     const _Float16* __restrict__ w16,
                                                     const float* __restrict__ bias,
                                                     _Float16* __restrict__ xproj) {
    __shared__ __align__(16) _Float16 As[128 * 64];
    __shared__ __align__(16) _Float16 Bs[128 * 64];

    const int tid = threadIdx.x;
    const int bx  = blockIdx.x;
    const int nt = bx & 15, mt = bx >> 4;
    const long m0 = (long)mt * 128;
    const long n0 = (long)nt * 128;
    const int lane = tid & 63, w = tid >> 6;
    const int ln15 = lane & 15, kg = lane >> 4;
    const int wr = (w >> 1) * 64, wc = (w & 1) * 64;

    int xr[4];
#pragma unroll
    for (int it = 0; it < 4; ++it) xr[it] = x[m0 + ((it * 256 + tid) >> 3)];

    float4v acc[4][4];
#pragma unroll
    for (int m = 0; m < 4; ++m)
#pragma unroll
        for (int n = 0; n < 4; ++n) acc[m][n] = (float4v){0.f, 0.f, 0.f, 0.f};

    for (int kt = 0; kt < 32; ++kt) {
        __syncthreads();
#pragma unroll
        for (int it = 0; it < 4; ++it) {
            int c = it * 256 + tid;
            const float* src = emb + (long)xr[it] * EMBD + kt * 64 + (c & 7) * 8;
            float4v v0 = *(const float4v*)src;
            float4v v1 = *(const float4v*)(src + 4);
            half8 hv;
#pragma unroll
            for (int q = 0; q < 4; ++q) { hv[q] = (_Float16)v0[q]; hv[4 + q] = (_Float16)v1[q]; }
            *(half8*)(&As[c * 8]) = hv;
        }
#pragma unroll
        for (int it = 0; it < 4; ++it) {
            int c = it * 256 + tid;
            const _Float16* src = w16 + (n0 + (c >> 3)) * (long)EMBD + kt * 64 + (c & 7) * 8;
            *(half8*)(&Bs[c * 8]) = *(const half8*)src;
        }
        __syncthreads();
#pragma unroll
        for (int kk = 0; kk < 2; ++kk) {
            half8 a[4], b[4];
#pragma unroll
            for (int m = 0; m < 4; ++m)
                a[m] = *(half8*)(&As[(wr + m * 16 + ln15) * 64 + kk * 32 + kg * 8]);
#pragma unroll
            for (int n = 0; n < 4; ++n)
                b[n] = *(half8*)(&Bs[(wc + n * 16 + ln15) * 64 + kk * 32 + kg * 8]);
            // swapped operands -> transposed fragment: lane holds 4 consecutive cols
#pragma unroll
            for (int m = 0; m < 4; ++m)
#pragma unroll
                for (int n = 0; n < 4; ++n)
                    acc[m][n] = __builtin_amdgcn_mfma_f32_16x16x32_f16(b[n], a[m], acc[m][n], 0, 0, 0);
        }
    }
#pragma unroll
    for (int m = 0; m < 4; ++m) {
        long mg = m0 + wr + m * 16 + ln15;
#pragma unroll
        for (int n = 0; n < 4; ++n) {
            int nb = (int)n0 + wc + n * 16 + kg * 4;
            float4v bv = *(const float4v*)(bias + nb);
            union { half4v h; unsigned long long u; } pk;
#pragma unroll
            for (int r = 0; r < 4; ++r) pk.h[r] = (_Float16)(acc[m][n][r] + bv[r]);
            *(unsigned long long*)(xproj + mg * HID + nb) = pk.u;
        }
    }
}

// ---------------- Phase B: persistent scan — R9 protocol + per-wave split gate ------
// 256 blocks x 256 thr. gid=bx&3 owns rows [32g,+32); sub=bx>>2 owns cols [32c,+32).
// Wave (pr=w>>1, kh=w&1): 16 rows x 32 cols x k-half; LDS part-reduce (stride 33).
// Slot-chain: bias[s] in xb slot s+1 (sc1 reads, never cached); h_{s+1} -> slot s
// (sc1 store; slot provably dead). Post-gate h reads plain cacheable (L2-shared).
// SPLIT GATE (strict relaxation of R9): wave kh consumes K in [1024kh,+1024) which
// is produced by blocks sub in [32kh,+32) only -> gate on those 32 flags (16 u64
// loads). K-half skew no longer cross-couples waves. All else identical to R9.
__global__ __launch_bounds__(256, 1) void scan_kernel(_Float16* __restrict__ xb,
                                                      const _Float16* __restrict__ whh,
                                                      float* __restrict__ hlast,
                                                      unsigned* __restrict__ flags) {
    __shared__ __align__(16) _Float16 Wl[32 * 2048];  // 128 KB
    __shared__ float part[4][16 * 33];

    const int tid = threadIdx.x;
    const int bx = blockIdx.x;
    const int gid = bx & 3, sub = bx >> 2;
    const int m0 = gid * 32, n0 = sub * 32;
    const int lane = tid & 63, w = tid >> 6;
    const int ln15 = lane & 15, kg = lane >> 4;
    const int pr = w >> 1, kh = w & 1;

    // stage W[n0..n0+32) x [0..2048): byte = col*4096 + ((k*2) ^ ((col&7)<<4))
    for (int it = 0; it < 32; ++it) {
        int c = it * 256 + tid;
        int col = c >> 8, ch = c & 255;
        half8 v = *(const half8*)(whh + (long)(n0 + col) * HID + ch * 8);
        *(half8*)((char*)Wl + col * 4096 + ((ch * 16) ^ ((col & 7) << 4))) = v;
    }
    __syncthreads();

    unsigned* gfl = flags + gid * 64;                       // 64 flags per group
    const unsigned long long* gfl64 = (const unsigned long long*)gfl;
    const size_t arow = (size_t)(m0 + pr * 16 + ln15);      // h row this lane loads
    const int wb0 = ln15 * 4096, wb1 = (16 + ln15) * 4096;  // W LDS row bases
    const int swz = (ln15 & 7) << 4;
    const int kb = kh * 2048;                               // k-half byte offset
    const int rp = tid >> 7, ridx = tid & 127;              // reduce/output mapping
    const int rrow = ridx >> 3, rc4 = (ridx & 7) * 4;
    const size_t oidx = (size_t)(m0 + rp * 16 + rrow) * HID + n0 + rc4;

    for (int s = 0; s < TSTEPS; ++s) {
        // bias[s] from slot s+1 — sc1 bypass (keeps slot out of all caches)
        unsigned long long xbits = __hip_atomic_load(
            (const unsigned long long*)(xb + (size_t)(s + 1) * STEP + oidx),
            __ATOMIC_RELAXED, __HIP_MEMORY_SCOPE_AGENT);

        float4v acc0 = (float4v){0.f, 0.f, 0.f, 0.f};
        float4v acc1 = (float4v){0.f, 0.f, 0.f, 0.f};
        if (s > 0) {
            // ---- split gate: this wave's 32 K-half producers >= s (16 u64 loads)
            for (;;) {
                bool ok = true;
                if (lane < 16) {
                    unsigned long long v = __hip_atomic_load(gfl64 + kh * 16 + lane,
                                            __ATOMIC_RELAXED, __HIP_MEMORY_SCOPE_AGENT);
                    ok = ((unsigned)v >= (unsigned)s) && ((unsigned)(v >> 32) >= (unsigned)s);
                }
                if (__all(ok)) break;
                __builtin_amdgcn_s_sleep(2);
            }
            asm volatile("" ::: "memory");        // no hoisting h loads above gate
            __builtin_amdgcn_sched_barrier(0);

            // ---- h_s from slot s-1: plain cacheable loads (L2-shared per XCD)
            const _Float16* hrow = xb + (size_t)(s - 1) * STEP + arow * HID + kh * 1024;
#pragma unroll
            for (int j = 0; j < 32; ++j) {
                half8 a = *(const half8*)(hrow + j * 32 + kg * 8);
                int k2 = kb + j * 64 + kg * 16;
                half8 b0 = *(half8*)((char*)Wl + wb0 + (k2 ^ swz));
                half8 b1 = *(half8*)((char*)Wl + wb1 + (k2 ^ swz));
                acc0 = __builtin_amdgcn_mfma_f32_16x16x32_f16(a, b0, acc0, 0, 0, 0);
                acc1 = __builtin_amdgcn_mfma_f32_16x16x32_f16(a, b1, acc1, 0, 0, 0);
            }
            // partials to LDS (stride 33)
#pragma unroll
            for (int r = 0; r < 4; ++r) {
                part[w][(kg * 4 + r) * 33 + ln15] = acc0[r];
                part[w][(kg * 4 + r) * 33 + 16 + ln15] = acc1[r];
            }
        }

        float s0 = 0.f, s1 = 0.f, s2 = 0.f, s3 = 0.f;
        if (s > 0) {
            __syncthreads();
            const float* p0 = &part[2 * rp][rrow * 33 + rc4];
            const float* p1 = &part[2 * rp + 1][rrow * 33 + rc4];
            s0 = p0[0] + p1[0]; s1 = p0[1] + p1[1];
            s2 = p0[2] + p1[2]; s3 = p0[3] + p1[3];
        }
        union { unsigned long long u; half4v h; } xbv; xbv.u = xbits;
        float o0 = tanhf(s0 + (float)xbv.h[0]);
        float o1 = tanhf(s1 + (float)xbv.h[1]);
        float o2 = tanhf(s2 + (float)xbv.h[2]);
        float o3 = tanhf(s3 + (float)xbv.h[3]);

        if (s < TSTEPS - 1) {
            // h_{s+1} -> slot s (sc1 fire-and-forget)
            union { half4v h; unsigned long long u; } pk;
            pk.h[0] = (_Float16)o0; pk.h[1] = (_Float16)o1;
            pk.h[2] = (_Float16)o2; pk.h[3] = (_Float16)o3;
            __hip_atomic_store((unsigned long long*)(xb + (size_t)s * STEP + oidx),
                               pk.u, __ATOMIC_RELAXED, __HIP_MEMORY_SCOPE_AGENT);
            // syncthreads drains vmcnt: all h stores acked at L3 before the flag.
            // Also the WAR guard for part[].
            __syncthreads();
            if (tid == 0)
                __hip_atomic_store(&gfl[sub], (unsigned)(s + 1),
                                   __ATOMIC_RELAXED, __HIP_MEMORY_SCOPE_AGENT);
        } else {
            float4v f = {o0, o1, o2, o3};
            *(float4v*)(hlast + oidx) = f;
        }
    }
}

// ---------------- head ----------------
// fc1 tiled: 16 blocks x 8 batch rows; fc1w read ONCE per block (32MB total)
__global__ __launch_bounds__(256) void fc1_kernel(const float* __restrict__ hlast,
                                                  const float* __restrict__ w,
                                                  const float* __restrict__ b,
                                                  float* __restrict__ z) {
    __shared__ float hs[8][256];
    const int blk = blockIdx.x;
    const int j = threadIdx.x;
    const int bb0 = blk * 8;
    float acc[8];
#pragma unroll
    for (int r = 0; r < 8; ++r) acc[r] = 0.f;
    const float* wr = w + (long)j * HID;
    const int sr = j >> 5, sc = (j & 31) * 8;

    for (int kt = 0; kt < 8; ++kt) {
        __syncthreads();
        float4v h0 = *(const float4v*)(hlast + (long)(bb0 + sr) * HID + kt * 256 + sc);
        float4v h1 = *(const float4v*)(hlast + (long)(bb0 + sr) * HID + kt * 256 + sc + 4);
        *(float4v*)&hs[sr][sc] = h0;
        *(float4v*)&hs[sr][sc + 4] = h1;
        __syncthreads();
        for (int k = 0; k < 256; k += 4) {
            float4v wv = *(const float4v*)(wr + kt * 256 + k);
#pragma unroll
            for (int r = 0; r < 8; ++r) {
                float4v hv = *(const float4v*)&hs[r][k];
                acc[r] += hv[0] * wv[0] + hv[1] * wv[1] + hv[2] * wv[2] + hv[3] * wv[3];
            }
        }
    }
    float bj = b[j];
#pragma unroll
    for (int r = 0; r < 8; ++r) z[(bb0 + r) * 256 + j] = fmaxf(acc[r] + bj, 0.f);
}

__global__ __launch_bounds__(256) void fc2_kernel(const float* __restrict__ z,
                                                  const float* __restrict__ w,
                                                  const float* __restrict__ b,
                                                  float* __restrict__ out) {
    __shared__ float red[4];
    int bb = blockIdx.x;
    int tid = threadIdx.x;
    float zv = z[bb * 256 + tid];
    for (int c = 0; c < 3; ++c) {
        float s = zv * w[c * 256 + tid];
        for (int off = 32; off > 0; off >>= 1) s += __shfl_down(s, off, 64);
        if ((tid & 63) == 0) red[tid >> 6] = s;
        __syncthreads();
        if (tid == 0) out[bb * 3 + c] = red[0] + red[1] + red[2] + red[3] + b[c];
        __syncthreads();
    }
}

// ---------------- launch ----------------
extern "C" void kernel_launch(void* const* d_in, const int* in_sizes, int n_in,
                              void* d_out, int out_size, void* d_ws, size_t ws_size,
                              hipStream_t stream) {
    const int*   x    = (const int*)d_in[0];
    const float* emb  = (const float*)d_in[1];
    const float* Wih  = (const float*)d_in[2];
    const float* Whh  = (const float*)d_in[3];
    const float* bih  = (const float*)d_in[4];
    const float* bhh  = (const float*)d_in[5];
    const float* fc1w = (const float*)d_in[6];
    const float* fc1b = (const float*)d_in[7];
    const float* fc2w = (const float*)d_in[8];
    const float* fc2b = (const float*)d_in[9];
    float* out = (float*)d_out;

    char* ws = (char*)d_ws;
    size_t off = 0;
    _Float16* xb    = (_Float16*)(ws + off); off += 257 * STEP * 2;         // 134.7 MB
    _Float16* wih16 = (_Float16*)(ws + off); off += (size_t)HID * EMBD * 2; // 8 MB
    _Float16* whh16 = (_Float16*)(ws + off); off += (size_t)HID * HID * 2;  // 8 MB
    float*    bias  = (float*)(ws + off);    off += (size_t)HID * 4;
    float*    hlast = (float*)(ws + off);    off += (size_t)BATCH * HID * 4;
    float*    z     = (float*)(ws + off);    off += (size_t)BATCH * 256 * 4;
    unsigned* flags = (unsigned*)(ws + off); off += 4 * 64 * 4;  // 1 KB

    hipMemsetAsync(flags, 0, 4 * 64 * 4, stream);

    cast_f16_kernel<<<4096, 256, 0, stream>>>(Wih, wih16, HID * EMBD);
    cast_f16_kernel<<<4096, 256, 0, stream>>>(Whh, whh16, HID * HID);
    bias_kernel<<<8, 256, 0, stream>>>(bih, bhh, bias);

    // phaseA writes bias[s] into slot s+1
    phaseA_kernel<<<4096, 256, 0, stream>>>(x, emb, wih16, bias, xb + STEP);

    void* args[] = {(void*)&xb, (void*)&whh16, (void*)&hlast, (void*)&flags};
    hipLaunchCooperativeKernel((const void*)scan_kernel, dim3(256), dim3(256), args, 0, stream);

    fc1_kernel<<<16, 256, 0, stream>>>(hlast, fc1w, fc1b, z);
    fc2_kernel<<<BATCH, 256, 0, stream>>>(z, fc2w, fc2b, out);
}

// Round 17
// 2579.663 us; speedup vs baseline: 3.7664x; 1.0357x over previous
//
#include <hip/hip_runtime.h>

typedef _Float16 half8 __attribute__((ext_vector_type(8)));
typedef _Float16 half4v __attribute__((ext_vector_type(4)));
typedef float float4v __attribute__((ext_vector_type(4)));

#define HID 2048
#define EMBD 2048
#define BATCH 128
#define TSTEPS 256
#define STEP ((size_t)BATCH * HID)

// ---------------- small prep kernels ----------------
__global__ __launch_bounds__(256) void cast_f16_kernel(const float* __restrict__ src,
                                                       _Float16* __restrict__ dst, int n) {
    int i = (blockIdx.x * 256 + threadIdx.x) * 4;
    int stride = gridDim.x * 256 * 4;
    for (; i < n; i += stride) {
        float4v v = *(const float4v*)(src + i);
        half4v h;
        h[0] = (_Float16)v[0]; h[1] = (_Float16)v[1];
        h[2] = (_Float16)v[2]; h[3] = (_Float16)v[3];
        *(half4v*)(dst + i) = h;
    }
}

__global__ __launch_bounds__(256) void bias_kernel(const float* __restrict__ a,
                                                   const float* __restrict__ b,
                                                   float* __restrict__ dst) {
    int i = blockIdx.x * 256 + threadIdx.x;
    if (i < HID) dst[i] = a[i] + b[i];
}

// ---------------- Phase A: slots 1..256 of xb = gather(emb,x) @ W_ih^T + bias ----------
// (R9-proven manual staging)
__global__ __launch_bounds__(256) void phaseA_kernel(const int* __restrict__ x,
                                                     const float* __restrict__ emb,
                                                     const _Float16* __restrict__ w16,
                                                     const float* __restrict__ bias,
                                                     _Float16* __restrict__ xproj) {
    __shared__ __align__(16) _Float16 As[128 * 64];
    __shared__ __align__(16) _Float16 Bs[128 * 64];

    const int tid = threadIdx.x;
    const int bx  = blockIdx.x;
    const int nt = bx & 15, mt = bx >> 4;
    const long m0 = (long)mt * 128;
    const long n0 = (long)nt * 128;
    const int lane = tid & 63, w = tid >> 6;
    const int ln15 = lane & 15, kg = lane >> 4;
    const int wr = (w >> 1) * 64, wc = (w & 1) * 64;

    int xr[4];
#pragma unroll
    for (int it = 0; it < 4; ++it) xr[it] = x[m0 + ((it * 256 + tid) >> 3)];

    float4v acc[4][4];
#pragma unroll
    for (int m = 0; m < 4; ++m)
#pragma unroll
        for (int n = 0; n < 4; ++n) acc[m][n] = (float4v){0.f, 0.f, 0.f, 0.f};

    for (int kt = 0; kt < 32; ++kt) {
        __syncthreads();
#pragma unroll
        for (int it = 0; it < 4; ++it) {
            int c = it * 256 + tid;
            const float* src = emb + (long)xr[it] * EMBD + kt * 64 + (c & 7) * 8;
            float4v v0 = *(const float4v*)src;
            float4v v1 = *(const float4v*)(src + 4);
            half8 hv;
#pragma unroll
            for (int q = 0; q < 4; ++q) { hv[q] = (_Float16)v0[q]; hv[4 + q] = (_Float16)v1[q]; }
            *(half8*)(&As[c * 8]) = hv;
        }
#pragma unroll
        for (int it = 0; it < 4; ++it) {
            int c = it * 256 + tid;
            const _Float16* src = w16 + (n0 + (c >> 3)) * (long)EMBD + kt * 64 + (c & 7) * 8;
            *(half8*)(&Bs[c * 8]) = *(const half8*)src;
        }
        __syncthreads();
#pragma unroll
        for (int kk = 0; kk < 2; ++kk) {
            half8 a[4], b[4];
#pragma unroll
            for (int m = 0; m < 4; ++m)
                a[m] = *(half8*)(&As[(wr + m * 16 + ln15) * 64 + kk * 32 + kg * 8]);
#pragma unroll
            for (int n = 0; n < 4; ++n)
                b[n] = *(half8*)(&Bs[(wc + n * 16 + ln15) * 64 + kk * 32 + kg * 8]);
            // swapped operands -> transposed fragment: lane holds 4 consecutive cols
#pragma unroll
            for (int m = 0; m < 4; ++m)
#pragma unroll
                for (int n = 0; n < 4; ++n)
                    acc[m][n] = __builtin_amdgcn_mfma_f32_16x16x32_f16(b[n], a[m], acc[m][n], 0, 0, 0);
        }
    }
#pragma unroll
    for (int m = 0; m < 4; ++m) {
        long mg = m0 + wr + m * 16 + ln15;
#pragma unroll
        for (int n = 0; n < 4; ++n) {
            int nb = (int)n0 + wc + n * 16 + kg * 4;
            float4v bv = *(const float4v*)(bias + nb);
            union { half4v h; unsigned long long u; } pk;
#pragma unroll
            for (int r = 0; r < 4; ++r) pk.h[r] = (_Float16)(acc[m][n][r] + bv[r]);
            *(unsigned long long*)(xproj + mg * HID + nb) = pk.u;
        }
    }
}

// ---------------- Phase B: persistent scan — R9 protocol VERBATIM (measured 1950us) --
// 256 blocks x 256 thr. gid=bx&3 owns rows [32g,+32); sub=bx>>2 owns cols [32c,+32).
// Wave (pr=w>>1, kh=w&1): 16 rows x 32 cols x k-half; LDS part-reduce (stride 33).
// Slot-chain: bias[s] in xb slot s+1 (sc1 reads, never cached); h_{s+1} -> slot s
// (sc1 store; slot provably dead). Gate: all 64 group flags >= s, all-wave poll
// (32 u64-lanes, s_sleep(2)-paced) — R11/R12/R16 gate variants all regressed;
// this exact form is the measured local optimum. Post-gate h reads are plain
// cacheable (first-touch -> L2-shared per XCD).
__global__ __launch_bounds__(256, 1) void scan_kernel(_Float16* __restrict__ xb,
                                                      const _Float16* __restrict__ whh,
                                                      float* __restrict__ hlast,
                                                      unsigned* __restrict__ flags) {
    __shared__ __align__(16) _Float16 Wl[32 * 2048];  // 128 KB
    __shared__ float part[4][16 * 33];

    const int tid = threadIdx.x;
    const int bx = blockIdx.x;
    const int gid = bx & 3, sub = bx >> 2;
    const int m0 = gid * 32, n0 = sub * 32;
    const int lane = tid & 63, w = tid >> 6;
    const int ln15 = lane & 15, kg = lane >> 4;
    const int pr = w >> 1, kh = w & 1;

    // stage W[n0..n0+32) x [0..2048): byte = col*4096 + ((k*2) ^ ((col&7)<<4))
    for (int it = 0; it < 32; ++it) {
        int c = it * 256 + tid;
        int col = c >> 8, ch = c & 255;
        half8 v = *(const half8*)(whh + (long)(n0 + col) * HID + ch * 8);
        *(half8*)((char*)Wl + col * 4096 + ((ch * 16) ^ ((col & 7) << 4))) = v;
    }
    __syncthreads();

    unsigned* gfl = flags + gid * 64;                       // 64 flags per group
    const unsigned long long* gfl64 = (const unsigned long long*)gfl;
    const size_t arow = (size_t)(m0 + pr * 16 + ln15);      // h row this lane loads
    const int wb0 = ln15 * 4096, wb1 = (16 + ln15) * 4096;  // W LDS row bases
    const int swz = (ln15 & 7) << 4;
    const int kb = kh * 2048;                               // k-half byte offset
    const int rp = tid >> 7, ridx = tid & 127;              // reduce/output mapping
    const int rrow = ridx >> 3, rc4 = (ridx & 7) * 4;
    const size_t oidx = (size_t)(m0 + rp * 16 + rrow) * HID + n0 + rc4;

    for (int s = 0; s < TSTEPS; ++s) {
        // bias[s] from slot s+1 — sc1 bypass (keeps slot out of all caches)
        unsigned long long xbits = __hip_atomic_load(
            (const unsigned long long*)(xb + (size_t)(s + 1) * STEP + oidx),
            __ATOMIC_RELAXED, __HIP_MEMORY_SCOPE_AGENT);

        float4v acc0 = (float4v){0.f, 0.f, 0.f, 0.f};
        float4v acc1 = (float4v){0.f, 0.f, 0.f, 0.f};
        if (s > 0) {
            // ---- gate: all 64 producer flags of this group >= s (all-wave poll)
            for (;;) {
                bool ok = true;
                if (lane < 32) {
                    unsigned long long v = __hip_atomic_load(gfl64 + lane,
                                            __ATOMIC_RELAXED, __HIP_MEMORY_SCOPE_AGENT);
                    ok = ((unsigned)v >= (unsigned)s) && ((unsigned)(v >> 32) >= (unsigned)s);
                }
                if (__all(ok)) break;
                __builtin_amdgcn_s_sleep(2);
            }
            asm volatile("" ::: "memory");        // no hoisting h loads above gate
            __builtin_amdgcn_sched_barrier(0);

            // ---- h_s from slot s-1: plain cacheable loads (L2-shared per XCD)
            const _Float16* hrow = xb + (size_t)(s - 1) * STEP + arow * HID + kh * 1024;
#pragma unroll
            for (int j = 0; j < 32; ++j) {
                half8 a = *(const half8*)(hrow + j * 32 + kg * 8);
                int k2 = kb + j * 64 + kg * 16;
                half8 b0 = *(half8*)((char*)Wl + wb0 + (k2 ^ swz));
                half8 b1 = *(half8*)((char*)Wl + wb1 + (k2 ^ swz));
                acc0 = __builtin_amdgcn_mfma_f32_16x16x32_f16(a, b0, acc0, 0, 0, 0);
                acc1 = __builtin_amdgcn_mfma_f32_16x16x32_f16(a, b1, acc1, 0, 0, 0);
            }
            // partials to LDS (stride 33)
#pragma unroll
            for (int r = 0; r < 4; ++r) {
                part[w][(kg * 4 + r) * 33 + ln15] = acc0[r];
                part[w][(kg * 4 + r) * 33 + 16 + ln15] = acc1[r];
            }
        }

        float s0 = 0.f, s1 = 0.f, s2 = 0.f, s3 = 0.f;
        if (s > 0) {
            __syncthreads();
            const float* p0 = &part[2 * rp][rrow * 33 + rc4];
            const float* p1 = &part[2 * rp + 1][rrow * 33 + rc4];
            s0 = p0[0] + p1[0]; s1 = p0[1] + p1[1];
            s2 = p0[2] + p1[2]; s3 = p0[3] + p1[3];
        }
        union { unsigned long long u; half4v h; } xbv; xbv.u = xbits;
        float o0 = tanhf(s0 + (float)xbv.h[0]);
        float o1 = tanhf(s1 + (float)xbv.h[1]);
        float o2 = tanhf(s2 + (float)xbv.h[2]);
        float o3 = tanhf(s3 + (float)xbv.h[3]);

        if (s < TSTEPS - 1) {
            // h_{s+1} -> slot s (sc1 fire-and-forget)
            union { half4v h; unsigned long long u; } pk;
            pk.h[0] = (_Float16)o0; pk.h[1] = (_Float16)o1;
            pk.h[2] = (_Float16)o2; pk.h[3] = (_Float16)o3;
            __hip_atomic_store((unsigned long long*)(xb + (size_t)s * STEP + oidx),
                               pk.u, __ATOMIC_RELAXED, __HIP_MEMORY_SCOPE_AGENT);
            // syncthreads drains vmcnt: all h stores acked at L3 before the flag.
            // Also the WAR guard for part[].
            __syncthreads();
            if (tid == 0)
                __hip_atomic_store(&gfl[sub], (unsigned)(s + 1),
                                   __ATOMIC_RELAXED, __HIP_MEMORY_SCOPE_AGENT);
        } else {
            float4v f = {o0, o1, o2, o3};
            *(float4v*)(hlast + oidx) = f;
        }
    }
}

// ---------------- head ----------------
// fc1 tiled: 16 blocks x 8 batch rows; fc1w read ONCE per block (32MB total)
__global__ __launch_bounds__(256) void fc1_kernel(const float* __restrict__ hlast,
                                                  const float* __restrict__ w,
                                                  const float* __restrict__ b,
                                                  float* __restrict__ z) {
    __shared__ float hs[8][256];
    const int blk = blockIdx.x;
    const int j = threadIdx.x;
    const int bb0 = blk * 8;
    float acc[8];
#pragma unroll
    for (int r = 0; r < 8; ++r) acc[r] = 0.f;
    const float* wr = w + (long)j * HID;
    const int sr = j >> 5, sc = (j & 31) * 8;

    for (int kt = 0; kt < 8; ++kt) {
        __syncthreads();
        float4v h0 = *(const float4v*)(hlast + (long)(bb0 + sr) * HID + kt * 256 + sc);
        float4v h1 = *(const float4v*)(hlast + (long)(bb0 + sr) * HID + kt * 256 + sc + 4);
        *(float4v*)&hs[sr][sc] = h0;
        *(float4v*)&hs[sr][sc + 4] = h1;
        __syncthreads();
        for (int k = 0; k < 256; k += 4) {
            float4v wv = *(const float4v*)(wr + kt * 256 + k);
#pragma unroll
            for (int r = 0; r < 8; ++r) {
                float4v hv = *(const float4v*)&hs[r][k];
                acc[r] += hv[0] * wv[0] + hv[1] * wv[1] + hv[2] * wv[2] + hv[3] * wv[3];
            }
        }
    }
    float bj = b[j];
#pragma unroll
    for (int r = 0; r < 8; ++r) z[(bb0 + r) * 256 + j] = fmaxf(acc[r] + bj, 0.f);
}

__global__ __launch_bounds__(256) void fc2_kernel(const float* __restrict__ z,
                                                  const float* __restrict__ w,
                                                  const float* __restrict__ b,
                                                  float* __restrict__ out) {
    __shared__ float red[4];
    int bb = blockIdx.x;
    int tid = threadIdx.x;
    float zv = z[bb * 256 + tid];
    for (int c = 0; c < 3; ++c) {
        float s = zv * w[c * 256 + tid];
        for (int off = 32; off > 0; off >>= 1) s += __shfl_down(s, off, 64);
        if ((tid & 63) == 0) red[tid >> 6] = s;
        __syncthreads();
        if (tid == 0) out[bb * 3 + c] = red[0] + red[1] + red[2] + red[3] + b[c];
        __syncthreads();
    }
}

// ---------------- launch ----------------
extern "C" void kernel_launch(void* const* d_in, const int* in_sizes, int n_in,
                              void* d_out, int out_size, void* d_ws, size_t ws_size,
                              hipStream_t stream) {
    const int*   x    = (const int*)d_in[0];
    const float* emb  = (const float*)d_in[1];
    const float* Wih  = (const float*)d_in[2];
    const float* Whh  = (const float*)d_in[3];
    const float* bih  = (const float*)d_in[4];
    const float* bhh  = (const float*)d_in[5];
    const float* fc1w = (const float*)d_in[6];
    const float* fc1b = (const float*)d_in[7];
    const float* fc2w = (const float*)d_in[8];
    const float* fc2b = (const float*)d_in[9];
    float* out = (float*)d_out;

    char* ws = (char*)d_ws;
    size_t off = 0;
    _Float16* xb    = (_Float16*)(ws + off); off += 257 * STEP * 2;         // 134.7 MB
    _Float16* wih16 = (_Float16*)(ws + off); off += (size_t)HID * EMBD * 2; // 8 MB
    _Float16* whh16 = (_Float16*)(ws + off); off += (size_t)HID * HID * 2;  // 8 MB
    float*    bias  = (float*)(ws + off);    off += (size_t)HID * 4;
    float*    hlast = (float*)(ws + off);    off += (size_t)BATCH * HID * 4;
    float*    z     = (float*)(ws + off);    off += (size_t)BATCH * 256 * 4;
    unsigned* flags = (unsigned*)(ws + off); off += 4 * 64 * 4;  // 1 KB

    hipMemsetAsync(flags, 0, 4 * 64 * 4, stream);

    cast_f16_kernel<<<4096, 256, 0, stream>>>(Wih, wih16, HID * EMBD);
    cast_f16_kernel<<<4096, 256, 0, stream>>>(Whh, whh16, HID * HID);
    bias_kernel<<<8, 256, 0, stream>>>(bih, bhh, bias);

    // phaseA writes bias[s] into slot s+1
    phaseA_kernel<<<4096, 256, 0, stream>>>(x, emb, wih16, bias, xb + STEP);

    void* args[] = {(void*)&xb, (void*)&whh16, (void*)&hlast, (void*)&flags};
    hipLaunchCooperativeKernel((const void*)scan_kernel, dim3(256), dim3(256), args, 0, stream);

    fc1_kernel<<<16, 256, 0, stream>>>(hlast, fc1w, fc1b, z);
    fc2_kernel<<<BATCH, 256, 0, stream>>>(z, fc2w, fc2b, out);
}